// Round 1
// baseline (76.761 us; speedup 1.0000x reference)
//
#include <hip/hip_runtime.h>

// Head_63101659513008: B=1024, x (B, 2B, 2) fp32, Wk/Wq/Wv (10,4,4) fp32,
// out (B, 2, 10) fp32.
//
// Algebra: with xr = x.view(B, B, 4), for each (b, head i):
//   out[b,0,i] = Vsum0 = sum_f xsum0[f] * wvsum[i,f]
//   out[b,1,i] = softmax(sc10, sc11) . (Vsum0, Vsum1)
// where (half h of rows: h=0 -> n in [0,512), h=1 -> n in [512,1024))
//   xsum_h[f]   = sum_j xr[b, 512h+j, f]
//   C1h[f][f']  = sum_j xr[b, 512+j, f] * xr[b, 512h+j, f']
//   sc1h        = sum_g sum_{f,f'} Wq[i,g,f] * Wk[i,g,f'] * C1h[f][f']
//   wvsum[i,f]  = sum_g Wv[i,g,f]
// Only 40 reduced floats per b are needed from the 16 KB x-slice.

#define NB 1024
#define NHEAD 10

__global__ __launch_bounds__(256) void head_kernel(
    const float* __restrict__ x,
    const float* __restrict__ Wk,
    const float* __restrict__ Wq,
    const float* __restrict__ Wv,
    float* __restrict__ out)
{
    const int b = blockIdx.x;
    const int tid = threadIdx.x;
    // xr[b] is (1024, 4) contiguous -> 1024 float4s starting at b*1024
    const float4* x4 = (const float4*)x + (size_t)b * 1024;

    // acc[0..15]  = C10[f][f']   (second half x first half)
    // acc[16..31] = C11[f][f']   (second half x second half)
    // acc[32..35] = xsum0[f], acc[36..39] = xsum1[f]
    float acc[40];
    #pragma unroll
    for (int k = 0; k < 40; ++k) acc[k] = 0.f;

    #pragma unroll
    for (int p = 0; p < 2; ++p) {
        const int n = tid + p * 256;          // j in [0, 512)
        const float4 a0 = x4[n];              // row j        (half 0)
        const float4 a1 = x4[512 + n];        // row 512 + j  (half 1)
        const float v0[4] = {a0.x, a0.y, a0.z, a0.w};
        const float v1[4] = {a1.x, a1.y, a1.z, a1.w};
        #pragma unroll
        for (int f = 0; f < 4; ++f) {
            acc[32 + f] += v0[f];
            acc[36 + f] += v1[f];
            #pragma unroll
            for (int fp = 0; fp < 4; ++fp) {
                acc[f * 4 + fp]      += v1[f] * v0[fp];
                acc[16 + f * 4 + fp] += v1[f] * v1[fp];
            }
        }
    }

    // 64-lane wave reduction of all 40 accumulators
    #pragma unroll
    for (int k = 0; k < 40; ++k) {
        float v = acc[k];
        #pragma unroll
        for (int off = 32; off > 0; off >>= 1)
            v += __shfl_down(v, off, 64);
        acc[k] = v;
    }

    __shared__ float red[4][40];
    __shared__ float fin[40];
    const int wave = tid >> 6;
    const int lane = tid & 63;
    if (lane == 0) {
        #pragma unroll
        for (int k = 0; k < 40; ++k) red[wave][k] = acc[k];
    }
    __syncthreads();
    if (tid < 40)
        fin[tid] = red[0][tid] + red[1][tid] + red[2][tid] + red[3][tid];
    __syncthreads();

    // per-head epilogue: threads 0..9
    if (tid < NHEAD) {
        const int i = tid;
        const float* wq = Wq + i * 16;   // [g*4 + f]
        const float* wk = Wk + i * 16;
        const float* wv = Wv + i * 16;

        float sc10 = 0.f, sc11 = 0.f;
        #pragma unroll
        for (int g = 0; g < 4; ++g) {
            #pragma unroll
            for (int f = 0; f < 4; ++f) {
                float a10 = 0.f, a11 = 0.f;
                #pragma unroll
                for (int fp = 0; fp < 4; ++fp) {
                    a10 += fin[f * 4 + fp]      * wk[g * 4 + fp];
                    a11 += fin[16 + f * 4 + fp] * wk[g * 4 + fp];
                }
                sc10 += wq[g * 4 + f] * a10;
                sc11 += wq[g * 4 + f] * a11;
            }
        }

        float wvf[4];
        #pragma unroll
        for (int f = 0; f < 4; ++f)
            wvf[f] = wv[f] + wv[4 + f] + wv[8 + f] + wv[12 + f];

        float vs0 = 0.f, vs1 = 0.f;
        #pragma unroll
        for (int f = 0; f < 4; ++f) {
            vs0 += fin[32 + f] * wvf[f];
            vs1 += fin[36 + f] * wvf[f];
        }

        // softmax over (sc10, sc11); masked row 0 is [1, 0]
        const float m  = fmaxf(sc10, sc11);
        const float e0 = __expf(sc10 - m);
        const float e1 = __expf(sc11 - m);
        const float inv = 1.f / (e0 + e1);

        out[b * 20 + i]      = vs0;                         // (b, t=0, i)
        out[b * 20 + 10 + i] = (e0 * vs0 + e1 * vs1) * inv; // (b, t=1, i)
    }
}

extern "C" void kernel_launch(void* const* d_in, const int* in_sizes, int n_in,
                              void* d_out, int out_size, void* d_ws, size_t ws_size,
                              hipStream_t stream)
{
    const float* x  = (const float*)d_in[0];
    const float* Wk = (const float*)d_in[1];
    const float* Wq = (const float*)d_in[2];
    const float* Wv = (const float*)d_in[3];
    float* out = (float*)d_out;
    head_kernel<<<NB, 256, 0, stream>>>(x, Wk, Wq, Wv, out);
}

// Round 2
// 69.599 us; speedup vs baseline: 1.1029x; 1.1029x over previous
//
#include <hip/hip_runtime.h>

// Head_63101659513008: B=1024, x (B, 2B, 2) fp32, Wk/Wq/Wv (10,4,4) fp32,
// out (B, 2, 10) fp32.
//
// Algebra: with xr = x.view(B, B, 4), for each (b, head i):
//   out[b,0,i] = Vsum0 = sum_f xsum0[f] * wvsum[i,f]
//   out[b,1,i] = softmax(sc10, sc11) . (Vsum0, Vsum1)
// where (half h: h=0 -> rows [0,512), h=1 -> rows [512,1024) of xr[b])
//   xsum_h[f]  = sum_j xr[b, 512h+j, f]
//   C1h[f][f'] = sum_j xr[b, 512+j, f] * xr[b, 512h+j, f']   (C11 symmetric!)
//   sc1h       = sum_g sum_{f,f'} Wq[i,g,f] * Wk[i,g,f'] * C1h[f][f']
//   wvsum[i,f] = sum_g Wv[i,g,f]
//
// R1 structure: 64 threads/block (1 wave) -> no LDS, no __syncthreads, and the
// per-wave shuffle-reduction tree is instantiated 4x less often than at 256
// threads (reduction VALU was co-dominant with the 6.5k-cycle/CU memory time).
// All 16 dwordx4 row loads are hoisted up front: ILP covers HBM latency at
// 1 wave/SIMD (64 KB in flight per CU >> BW-delay product ~9 KB).

#define NB 1024

__device__ __forceinline__ int TRI(int f, int fp) {  // fp >= f, both 0..3
    return f * (7 - f) / 2 + fp;                     // -> 0..9 upper-tri index
}

__global__ __launch_bounds__(64) void head_kernel(
    const float* __restrict__ x,
    const float* __restrict__ Wk,
    const float* __restrict__ Wq,
    const float* __restrict__ Wv,
    float* __restrict__ out)
{
    const int b = blockIdx.x;
    const int lane = threadIdx.x;                    // 0..63, one wave
    const float4* x4 = (const float4*)x + (size_t)b * 1024;

    // Issue all 16 global loads before any compute (explicit ILP).
    float4 A0[8], A1[8];
    #pragma unroll
    for (int p = 0; p < 8; ++p) {
        A0[p] = x4[lane + p * 64];                   // half 0 rows
        A1[p] = x4[512 + lane + p * 64];             // half 1 rows
    }

    // Prefetch head weights (lanes >= 10 redundantly load head 0; L2-hot).
    const int hi = lane < 10 ? lane : 0;
    float4 wq4[4], wk4[4], wv4[4];
    {
        const float4* q = (const float4*)(Wq + hi * 16);
        const float4* k = (const float4*)(Wk + hi * 16);
        const float4* v = (const float4*)(Wv + hi * 16);
        #pragma unroll
        for (int g = 0; g < 4; ++g) { wq4[g] = q[g]; wk4[g] = k[g]; wv4[g] = v[g]; }
    }

    // acc[0..15]  = C10[f][fp]        (Q-side half1 x K-side half0)
    // acc[16..25] = C11 upper tri     (symmetric)
    // acc[26..29] = xsum0, acc[30..33] = xsum1
    float acc[34];
    #pragma unroll
    for (int k = 0; k < 34; ++k) acc[k] = 0.f;

    #pragma unroll
    for (int p = 0; p < 8; ++p) {
        const float v0[4] = {A0[p].x, A0[p].y, A0[p].z, A0[p].w};
        const float v1[4] = {A1[p].x, A1[p].y, A1[p].z, A1[p].w};
        #pragma unroll
        for (int f = 0; f < 4; ++f) {
            acc[26 + f] += v0[f];
            acc[30 + f] += v1[f];
            #pragma unroll
            for (int fp = 0; fp < 4; ++fp)
                acc[f * 4 + fp] += v1[f] * v0[fp];
            #pragma unroll
            for (int fp = f; fp < 4; ++fp)
                acc[16 + TRI(f, fp)] += v1[f] * v1[fp];
        }
    }

    // Butterfly xor-reduce: every lane ends holding the block-wide sums.
    #pragma unroll
    for (int k = 0; k < 34; ++k) {
        float v = acc[k];
        #pragma unroll
        for (int off = 1; off < 64; off <<= 1)
            v += __shfl_xor(v, off, 64);
        acc[k] = v;
    }

    // Per-head epilogue straight from registers, lanes 0..9.
    if (lane < 10) {
        float wq[16], wk[16], wv[16];
        #pragma unroll
        for (int g = 0; g < 4; ++g) {
            wq[g*4+0] = wq4[g].x; wq[g*4+1] = wq4[g].y; wq[g*4+2] = wq4[g].z; wq[g*4+3] = wq4[g].w;
            wk[g*4+0] = wk4[g].x; wk[g*4+1] = wk4[g].y; wk[g*4+2] = wk4[g].z; wk[g*4+3] = wk4[g].w;
            wv[g*4+0] = wv4[g].x; wv[g*4+1] = wv4[g].y; wv[g*4+2] = wv4[g].z; wv[g*4+3] = wv4[g].w;
        }

        float sc10 = 0.f, sc11 = 0.f;
        #pragma unroll
        for (int f = 0; f < 4; ++f) {
            #pragma unroll
            for (int fp = 0; fp < 4; ++fp) {
                float qk = 0.f;                       // qk[f][fp] = sum_g Wq[g,f]*Wk[g,fp]
                #pragma unroll
                for (int g = 0; g < 4; ++g)
                    qk += wq[g * 4 + f] * wk[g * 4 + fp];
                const int lo = f < fp ? f : fp;
                const int hgh = f < fp ? fp : f;
                sc10 += qk * acc[f * 4 + fp];
                sc11 += qk * acc[16 + TRI(lo, hgh)];
            }
        }

        float wvf[4];
        #pragma unroll
        for (int f = 0; f < 4; ++f)
            wvf[f] = wv[f] + wv[4 + f] + wv[8 + f] + wv[12 + f];

        float vs0 = 0.f, vs1 = 0.f;
        #pragma unroll
        for (int f = 0; f < 4; ++f) {
            vs0 += acc[26 + f] * wvf[f];
            vs1 += acc[30 + f] * wvf[f];
        }

        // softmax over (sc10, sc11); causal row t=0 is exactly [1, 0].
        const float m  = fmaxf(sc10, sc11);
        const float e0 = __expf(sc10 - m);
        const float e1 = __expf(sc11 - m);
        const float r  = 1.f / (e0 + e1);

        out[b * 20 + lane]      = vs0;                        // (b, t=0, i)
        out[b * 20 + 10 + lane] = (e0 * vs0 + e1 * vs1) * r;  // (b, t=1, i)
    }
}

extern "C" void kernel_launch(void* const* d_in, const int* in_sizes, int n_in,
                              void* d_out, int out_size, void* d_ws, size_t ws_size,
                              hipStream_t stream)
{
    const float* x  = (const float*)d_in[0];
    const float* Wk = (const float*)d_in[1];
    const float* Wq = (const float*)d_in[2];
    const float* Wv = (const float*)d_in[3];
    float* out = (float*)d_out;
    head_kernel<<<NB, 64, 0, stream>>>(x, Wk, Wq, Wv, out);
}

// Round 3
// 68.633 us; speedup vs baseline: 1.1184x; 1.0141x over previous
//
#include <hip/hip_runtime.h>

// Head_63101659513008: B=1024, x (B, 2B, 2) fp32, Wk/Wq/Wv (10,4,4) fp32,
// out (B, 2, 10) fp32.
//
// Algebra: with xr = x.view(B, B, 4), for each (b, head i):
//   out[b,0,i] = Vsum0 = sum_f xsum0[f] * wvsum[i,f]
//   out[b,1,i] = softmax(sc10, sc11) . (Vsum0, Vsum1)
// where (half h: h=0 -> rows [0,512), h=1 -> rows [512,1024) of xr[b])
//   xsum_h[f]  = sum_j xr[b, 512h+j, f]
//   C1h[f][f'] = sum_j xr[b, 512+j, f] * xr[b, 512h+j, f']   (C11 symmetric)
//   sc1h       = sum_g sum_{f,f'} Wq[i,g,f] * Wk[i,g,f'] * C1h[f][f']
//   wvsum[i,f] = sum_g Wv[i,g,f]
//
// R2: 1 wave/block, hoisted dwordx4 loads, butterfly shfl_xor reduce.
// R3: replace the 34x6 ds_swizzle butterfly (DS pipe + lgkmcnt waits) with
// the classic gfx9 DPP-add ladder (row_shr 1/2/4/8 + row_bcast 15/31), all
// on the VALU pipe, then v_readlane lane 63 -> wave-uniform SGPR totals.

#define NB 1024

__device__ __forceinline__ int TRI(int f, int fp) {  // fp >= f, both 0..3
    return f * (7 - f) / 2 + fp;                     // -> 0..9 upper-tri index
}

template <int CTRL, int RM, int BM, bool BC>
__device__ __forceinline__ float dpp_add(float x) {
    int xi = __builtin_bit_cast(int, x);
    int yi = __builtin_amdgcn_update_dpp(0, xi, CTRL, RM, BM, BC);
    return x + __builtin_bit_cast(float, yi);
}

// Full-wave64 sum; returns the total as a wave-uniform value (SGPR).
__device__ __forceinline__ float wave_sum64(float x) {
    x = dpp_add<0x111, 0xf, 0xf, true>(x);   // row_shr:1  (OOB lanes read 0)
    x = dpp_add<0x112, 0xf, 0xf, true>(x);   // row_shr:2
    x = dpp_add<0x114, 0xf, 0xf, true>(x);   // row_shr:4
    x = dpp_add<0x118, 0xf, 0xf, true>(x);   // row_shr:8  -> lane 15 of each row = row sum
    x = dpp_add<0x142, 0xa, 0xf, false>(x);  // row_bcast:15 -> rows 1,3 accumulate
    x = dpp_add<0x143, 0xc, 0xf, false>(x);  // row_bcast:31 -> lane 63 = total
    return __builtin_bit_cast(float,
        __builtin_amdgcn_readlane(__builtin_bit_cast(int, x), 63));
}

__global__ __launch_bounds__(64) void head_kernel(
    const float* __restrict__ x,
    const float* __restrict__ Wk,
    const float* __restrict__ Wq,
    const float* __restrict__ Wv,
    float* __restrict__ out)
{
    const int b = blockIdx.x;
    const int lane = threadIdx.x;                    // 0..63, one wave
    const float4* x4 = (const float4*)x + (size_t)b * 1024;

    // Issue all 16 global loads before any compute (explicit ILP).
    float4 A0[8], A1[8];
    #pragma unroll
    for (int p = 0; p < 8; ++p) {
        A0[p] = x4[lane + p * 64];                   // half 0 rows
        A1[p] = x4[512 + lane + p * 64];             // half 1 rows
    }

    // Prefetch head weights (lanes >= 10 redundantly load head 0; L2-hot).
    const int hi = lane < 10 ? lane : 0;
    float4 wq4[4], wk4[4], wv4[4];
    {
        const float4* q = (const float4*)(Wq + hi * 16);
        const float4* k = (const float4*)(Wk + hi * 16);
        const float4* v = (const float4*)(Wv + hi * 16);
        #pragma unroll
        for (int g = 0; g < 4; ++g) { wq4[g] = q[g]; wk4[g] = k[g]; wv4[g] = v[g]; }
    }

    // acc[0..15]  = C10[f][fp]        (Q-side half1 x K-side half0)
    // acc[16..25] = C11 upper tri     (symmetric)
    // acc[26..29] = xsum0, acc[30..33] = xsum1
    float acc[34];
    #pragma unroll
    for (int k = 0; k < 34; ++k) acc[k] = 0.f;

    #pragma unroll
    for (int p = 0; p < 8; ++p) {
        const float v0[4] = {A0[p].x, A0[p].y, A0[p].z, A0[p].w};
        const float v1[4] = {A1[p].x, A1[p].y, A1[p].z, A1[p].w};
        #pragma unroll
        for (int f = 0; f < 4; ++f) {
            acc[26 + f] += v0[f];
            acc[30 + f] += v1[f];
            #pragma unroll
            for (int fp = 0; fp < 4; ++fp)
                acc[f * 4 + fp] += v1[f] * v0[fp];
            #pragma unroll
            for (int fp = f; fp < 4; ++fp)
                acc[16 + TRI(f, fp)] += v1[f] * v1[fp];
        }
    }

    // DPP wave reduction: 34 independent 6-deep VALU ladders (no DS pipe).
    float s[34];
    #pragma unroll
    for (int k = 0; k < 34; ++k) s[k] = wave_sum64(acc[k]);

    // Per-head epilogue from wave-uniform totals, lanes 0..9.
    if (lane < 10) {
        float wq[16], wk[16], wv[16];
        #pragma unroll
        for (int g = 0; g < 4; ++g) {
            wq[g*4+0] = wq4[g].x; wq[g*4+1] = wq4[g].y; wq[g*4+2] = wq4[g].z; wq[g*4+3] = wq4[g].w;
            wk[g*4+0] = wk4[g].x; wk[g*4+1] = wk4[g].y; wk[g*4+2] = wk4[g].z; wk[g*4+3] = wk4[g].w;
            wv[g*4+0] = wv4[g].x; wv[g*4+1] = wv4[g].y; wv[g*4+2] = wv4[g].z; wv[g*4+3] = wv4[g].w;
        }

        float sc10 = 0.f, sc11 = 0.f;
        #pragma unroll
        for (int f = 0; f < 4; ++f) {
            #pragma unroll
            for (int fp = 0; fp < 4; ++fp) {
                float qk = 0.f;                       // qk[f][fp] = sum_g Wq[g,f]*Wk[g,fp]
                #pragma unroll
                for (int g = 0; g < 4; ++g)
                    qk += wq[g * 4 + f] * wk[g * 4 + fp];
                const int lo = f < fp ? f : fp;
                const int hgh = f < fp ? fp : f;
                sc10 += qk * s[f * 4 + fp];
                sc11 += qk * s[16 + TRI(lo, hgh)];
            }
        }

        float wvf[4];
        #pragma unroll
        for (int f = 0; f < 4; ++f)
            wvf[f] = wv[f] + wv[4 + f] + wv[8 + f] + wv[12 + f];

        float vs0 = 0.f, vs1 = 0.f;
        #pragma unroll
        for (int f = 0; f < 4; ++f) {
            vs0 += s[26 + f] * wvf[f];
            vs1 += s[30 + f] * wvf[f];
        }

        // softmax over (sc10, sc11); causal row t=0 is exactly [1, 0].
        const float m  = fmaxf(sc10, sc11);
        const float e0 = __expf(sc10 - m);
        const float e1 = __expf(sc11 - m);
        const float r  = 1.f / (e0 + e1);

        out[b * 20 + lane]      = vs0;                        // (b, t=0, i)
        out[b * 20 + 10 + lane] = (e0 * vs0 + e1 * vs1) * r;  // (b, t=1, i)
    }
}

extern "C" void kernel_launch(void* const* d_in, const int* in_sizes, int n_in,
                              void* d_out, int out_size, void* d_ws, size_t ws_size,
                              hipStream_t stream)
{
    const float* x  = (const float*)d_in[0];
    const float* Wk = (const float*)d_in[1];
    const float* Wq = (const float*)d_in[2];
    const float* Wv = (const float*)d_in[3];
    float* out = (float*)d_out;
    head_kernel<<<NB, 64, 0, stream>>>(x, Wk, Wq, Wv, out);
}